// Round 14
// baseline (226.267 us; speedup 1.0000x reference)
//
#include <hip/hip_runtime.h>
#include <hip/hip_fp16.h>
#include <math.h>

#define N_NODES 100000
#define E_EDGES 1600000
#define D_IN    128
#define H_MID   32
#define C_OUT   5

#define BSHIFT 9
#define BNODES 512    // nodes per bucket
#define NBKT   196    // ceil(100000/512)
#define BCAP   9200   // per-bucket staging cap (mean 8163)
#define SRC_BITS 17
#define SRC_MASK 0x1FFFF

#define KP 136        // LDS k-stride in bf16 units (x-tile)

typedef __attribute__((ext_vector_type(8))) short bf16x8;
typedef __attribute__((ext_vector_type(4))) float f32x4;

// round-to-nearest-even fp32 -> bf16 bits
__device__ inline unsigned f2bf(float f) {
    unsigned u = __float_as_uint(f);
    return (u + 0x7FFFu + ((u >> 16) & 1u)) >> 16;
}
__device__ inline float bf2f(unsigned v) { return __uint_as_float(v << 16); }
__device__ inline unsigned short f2h(float f) {
    __half h = __float2half(f);
    return *(unsigned short*)&h;
}
__device__ inline float h2f(unsigned short u) {
    __half h = *(__half*)&u;
    return __half2float(h);
}

// ---------------- prep: zero cursors + build transposed bf16 W1 panel ------
__global__ void k_prep(const float* __restrict__ Wrel,
                       const float* __restrict__ Wroot,
                       int* __restrict__ bucket_cursor,
                       unsigned short* __restrict__ wt_g) {
    int tid = threadIdx.x;                 // 256
    bucket_cursor[tid] = 0;                // 256 >= NBKT
    for (int i = tid; i < 64 * 128; i += 256) {
        int n = i >> 7, k = i & 127;
        float v = (n < H_MID) ? Wrel[k * H_MID + n] : Wroot[k * H_MID + (n - H_MID)];
        wt_g[i] = (unsigned short)f2bf(v);   // wt_g[n][k]
    }
}

// ---------------- K1 (MFMA): [xrel|xroot(bf16)] = x @ [Wrel|Wroot] ----------
__global__ __launch_bounds__(256) void k1_mfma(
    const float* __restrict__ x,
    const unsigned short* __restrict__ wt_g,
    const float* __restrict__ b1,
    unsigned short* __restrict__ xrelh,
    unsigned short* __restrict__ xrooth) {
    __shared__ unsigned short xs[64 * KP];
    int tid = threadIdx.x;
    int nodeBase = blockIdx.x * 64;

    #pragma unroll
    for (int it = 0; it < 16; ++it) {
        int idx = it * 256 + tid;          // row*64 + kpair
        int row = idx >> 6, kp = idx & 63;
        int node = nodeBase + row;
        float2 v = make_float2(0.f, 0.f);
        if (node < N_NODES)
            v = *(const float2*)(x + (size_t)node * D_IN + kp * 2);
        unsigned pk = f2bf(v.x) | (f2bf(v.y) << 16);
        *(unsigned*)(xs + row * KP + kp * 2) = pk;
    }
    __syncthreads();

    int lane = tid & 63;
    int wv = tid >> 6;
    int m = lane & 15;
    int quad = lane >> 4;

    f32x4 acc[4];
    #pragma unroll
    for (int nt = 0; nt < 4; ++nt) acc[nt] = (f32x4){0.f, 0.f, 0.f, 0.f};

    #pragma unroll
    for (int kk = 0; kk < 4; ++kk) {
        int k0 = kk * 32 + quad * 8;
        bf16x8 a = *(const bf16x8*)(xs + (wv * 16 + m) * KP + k0);
        #pragma unroll
        for (int nt = 0; nt < 4; ++nt) {
            bf16x8 b = *(const bf16x8*)(wt_g + (nt * 16 + m) * 128 + k0);
            acc[nt] = __builtin_amdgcn_mfma_f32_16x16x32_bf16(a, b, acc[nt], 0, 0, 0);
        }
    }

    #pragma unroll
    for (int nt = 0; nt < 4; ++nt) {
        #pragma unroll
        for (int r = 0; r < 4; ++r) {
            int node = nodeBase + wv * 16 + quad * 4 + r;
            int colg = nt * 16 + m;
            if (node < N_NODES) {
                if (colg < H_MID) {
                    xrelh[(size_t)node * H_MID + colg] =
                        (unsigned short)f2bf(acc[nt][r]);
                } else {
                    int c = colg - H_MID;
                    xrooth[(size_t)node * H_MID + c] =
                        (unsigned short)f2bf(acc[nt][r] + b1[c]);
                }
            }
        }
    }
}

// -------- Pass A: counting-sort 2048 edges by coarse bucket in LDS --------
// staged SoA: staged_p int {(dstLow9 << 17) | src17}, staged_w fp16.
__global__ __launch_bounds__(1024) void k_binA(
    const int* __restrict__ src,
    const int* __restrict__ dst,
    const float* __restrict__ ew,
    int* __restrict__ bucket_cursor,
    int* __restrict__ staged_p,
    unsigned short* __restrict__ staged_w) {
    __shared__ int cnt[NBKT];
    __shared__ int lstart[NBKT];
    __shared__ int gbase[NBKT];
    __shared__ int scanbuf[256];
    __shared__ int ebuf_p[2048];
    __shared__ unsigned short ebuf_w[2048];
    __shared__ short bbuf[2048];
    int tid = threadIdx.x;
    int eBase = blockIdx.x * 2048;

    if (tid < NBKT) cnt[tid] = 0;
    __syncthreads();

    int b[2], rank[2], packed[2];
    unsigned short wh[2];
    bool valid[2];
    #pragma unroll
    for (int u = 0; u < 2; ++u) {
        int e = eBase + u * 1024 + tid;
        valid[u] = (e < E_EDGES);
        b[u] = 0; rank[u] = 0; packed[u] = 0; wh[u] = 0;
        if (valid[u]) {
            int d = dst[e];
            int s = src[e];
            wh[u] = f2h(ew[e]);
            b[u] = d >> BSHIFT;
            packed[u] = ((d & (BNODES - 1)) << SRC_BITS) | s;
            rank[u] = atomicAdd(&cnt[b[u]], 1);
        }
    }
    __syncthreads();

    if (tid < 256) scanbuf[tid] = (tid < NBKT) ? cnt[tid] : 0;
    __syncthreads();
    for (int off = 1; off < 256; off <<= 1) {
        int t = 0;
        if (tid < 256 && tid >= off) t = scanbuf[tid - off];
        __syncthreads();
        if (tid < 256) scanbuf[tid] += t;
        __syncthreads();
    }
    if (tid < NBKT) {
        lstart[tid] = scanbuf[tid] - cnt[tid];
        gbase[tid]  = atomicAdd(&bucket_cursor[tid], cnt[tid]);
    }
    __syncthreads();
    int total = scanbuf[NBKT - 1];

    #pragma unroll
    for (int u = 0; u < 2; ++u) {
        if (valid[u]) {
            int slot = lstart[b[u]] + rank[u];
            ebuf_p[slot] = packed[u];
            ebuf_w[slot] = wh[u];
            bbuf[slot] = (short)b[u];
        }
    }
    __syncthreads();

    for (int t = tid; t < total; t += 1024) {
        int bb = bbuf[t];
        int gpos = gbase[bb] + (t - lstart[bb]);
        if (gpos < BCAP) {
            size_t idx = (size_t)bb * BCAP + gpos;
            staged_p[idx] = ebuf_p[t];
            staged_w[idx] = ebuf_w[t];
        }
    }
}

// -------- Pass B: in-block base scan + per-bucket LDS hist + scatter -------
__global__ __launch_bounds__(1024) void k_binB2(
    const int* __restrict__ bucket_cursor,
    const int* __restrict__ staged_p,
    const unsigned short* __restrict__ staged_w,
    int* __restrict__ deg,
    int* __restrict__ offsets,
    int* __restrict__ csr_src,
    unsigned short* __restrict__ csr_w) {
    __shared__ int hist[BNODES];
    __shared__ int scanb[BNODES];
    __shared__ int cur[BNODES];
    __shared__ int sbase[256];
    int tid = threadIdx.x;
    int b = blockIdx.x;

    if (tid < 256) {
        int c = (tid < NBKT) ? bucket_cursor[tid] : 0;
        sbase[tid] = (c > BCAP) ? BCAP : c;
    }
    if (tid < BNODES) hist[tid] = 0;
    __syncthreads();
    for (int off = 1; off < 256; off <<= 1) {
        int t = 0;
        if (tid < 256 && tid >= off) t = sbase[tid - off];
        __syncthreads();
        if (tid < 256) sbase[tid] += t;
        __syncthreads();
    }
    int count = bucket_cursor[b];
    if (count > BCAP) count = BCAP;
    int base = sbase[b] - count;           // exclusive
    int nodeBase = b << BSHIFT;
    const int* sp = staged_p + (size_t)b * BCAP;
    const unsigned short* sw = staged_w + (size_t)b * BCAP;

    for (int i = tid; i < count; i += 1024)
        atomicAdd(&hist[((unsigned)sp[i]) >> SRC_BITS], 1);
    __syncthreads();

    int v = 0;
    if (tid < BNODES) {
        v = hist[tid];
        scanb[tid] = v;
    }
    __syncthreads();
    for (int off = 1; off < BNODES; off <<= 1) {
        int t = 0;
        if (tid < BNODES && tid >= off) t = scanb[tid - off];
        __syncthreads();
        if (tid < BNODES) scanb[tid] += t;
        __syncthreads();
    }
    if (tid < BNODES) {
        int excl = scanb[tid] - v;
        int node = nodeBase + tid;
        if (node < N_NODES) {
            deg[node]     = v;
            offsets[node] = base + excl;
        }
        cur[tid] = excl;
    }
    __syncthreads();

    for (int i = tid; i < count; i += 1024) {
        int p = sp[i];
        unsigned short w = sw[i];
        int local = ((unsigned)p) >> SRC_BITS;
        int pos = atomicAdd(&cur[local], 1);
        csr_src[base + pos] = p & SRC_MASK;
        csr_w[base + pos]   = w;
    }
}

// -------- Layer 1 fused: bf16 gather-mean + root + relu + project ----------
// 32 nodes/block (512 threads), 16 lanes/node, 2 cols/lane, 8-deep ILP.
__global__ __launch_bounds__(512) void k_layer1(
    const int* __restrict__ offsets,
    const int* __restrict__ deg,
    const int* __restrict__ csr_src,
    const unsigned short* __restrict__ csr_w,
    const unsigned short* __restrict__ xrelh,
    const unsigned short* __restrict__ xrooth,
    const float* __restrict__ Wrel2,
    const float* __restrict__ Wroot2,
    const float* __restrict__ b2,
    float* __restrict__ h2rel,
    float* __restrict__ h2root) {
    int node = blockIdx.x * 32 + (threadIdx.x >> 4);
    int lane = threadIdx.x & 15;           // 2 cols: 2*lane, 2*lane+1
    int beg = offsets[node];
    int dg  = deg[node];
    int end = beg + dg;

    float acc0 = 0.f, acc1 = 0.f;
    int i = beg;
    for (; i + 8 <= end; i += 8) {
        int s[8];
        unsigned short wh[8];
        unsigned v[8];
        #pragma unroll
        for (int u = 0; u < 8; ++u) s[u] = csr_src[i + u];
        #pragma unroll
        for (int u = 0; u < 8; ++u) wh[u] = csr_w[i + u];
        #pragma unroll
        for (int u = 0; u < 8; ++u)
            v[u] = *(const unsigned*)(xrelh + (size_t)s[u] * H_MID + lane * 2);
        #pragma unroll
        for (int u = 0; u < 8; ++u) {
            float w = h2f(wh[u]);
            acc0 += bf2f(v[u] & 0xFFFFu) * w;
            acc1 += __uint_as_float(v[u] & 0xFFFF0000u) * w;
        }
    }
    for (; i < end; ++i) {
        int s0 = csr_src[i];
        float w0 = h2f(csr_w[i]);
        unsigned v0 = *(const unsigned*)(xrelh + (size_t)s0 * H_MID + lane * 2);
        acc0 += bf2f(v0 & 0xFFFFu) * w0;
        acc1 += __uint_as_float(v0 & 0xFFFF0000u) * w0;
    }

    float inv = 1.0f / fmaxf((float)dg, 1.0f);
    unsigned rtv = *(const unsigned*)(xrooth + (size_t)node * H_MID + lane * 2);
    float h0 = fmaxf(acc0 * inv + bf2f(rtv & 0xFFFFu), 0.f);
    float h1 = fmaxf(acc1 * inv + __uint_as_float(rtv & 0xFFFF0000u), 0.f);

    float p[2 * C_OUT];
    #pragma unroll
    for (int j = 0; j < C_OUT; ++j) {
        p[j]         = h0 * Wrel2[(2 * lane) * C_OUT + j]
                     + h1 * Wrel2[(2 * lane + 1) * C_OUT + j];
        p[C_OUT + j] = h0 * Wroot2[(2 * lane) * C_OUT + j]
                     + h1 * Wroot2[(2 * lane + 1) * C_OUT + j];
    }
    #pragma unroll
    for (int mm = 8; mm > 0; mm >>= 1) {
        #pragma unroll
        for (int j = 0; j < 2 * C_OUT; ++j)
            p[j] += __shfl_xor(p[j], mm, 16);
    }
    if (lane == 0) {
        #pragma unroll
        for (int j = 0; j < C_OUT; ++j) {
            h2rel[(size_t)node * C_OUT + j]  = p[j];
            h2root[(size_t)node * C_OUT + j] = p[C_OUT + j] + b2[j];
        }
    }
}

// -------- Layer 2 + log_softmax fused: 32 nodes/block, 8 lanes/node --------
__global__ __launch_bounds__(256) void k_layer2(
    const int* __restrict__ offsets,
    const int* __restrict__ deg,
    const int* __restrict__ csr_src,
    const float* __restrict__ h2rel,
    const float* __restrict__ h2root,
    float* __restrict__ out) {
    int node = blockIdx.x * 32 + (threadIdx.x >> 3);
    int lane = threadIdx.x & 7;
    int beg = offsets[node];
    int dg  = deg[node];
    int end = beg + dg;

    float acc = 0.f;
    if (lane < C_OUT) {
        int i = beg;
        for (; i + 8 <= end; i += 8) {
            int s[8];
            float v[8];
            #pragma unroll
            for (int u = 0; u < 8; ++u) s[u] = csr_src[i + u];
            #pragma unroll
            for (int u = 0; u < 8; ++u)
                v[u] = h2rel[(size_t)s[u] * C_OUT + lane];
            #pragma unroll
            for (int u = 0; u < 8; ++u) acc += v[u];
        }
        for (; i < end; ++i)
            acc += h2rel[(size_t)csr_src[i] * C_OUT + lane];
    }
    float inv = 1.0f / fmaxf((float)dg, 1.0f);
    float o = (lane < C_OUT)
                  ? acc * inv + h2root[(size_t)node * C_OUT + lane]
                  : -INFINITY;
    float m = o;
    #pragma unroll
    for (int dd = 4; dd > 0; dd >>= 1) m = fmaxf(m, __shfl_xor(m, dd, 8));
    float e = (lane < C_OUT) ? expf(o - m) : 0.f;
    float ssum = e;
    #pragma unroll
    for (int dd = 4; dd > 0; dd >>= 1) ssum += __shfl_xor(ssum, dd, 8);
    float lse = m + logf(ssum);
    if (lane < C_OUT)
        out[(size_t)node * C_OUT + lane] = o - lse;
}

extern "C" void kernel_launch(void* const* d_in, const int* in_sizes, int n_in,
                              void* d_out, int out_size, void* d_ws, size_t ws_size,
                              hipStream_t stream) {
    const float* x      = (const float*)d_in[0];
    const int*   ei     = (const int*)d_in[1];
    const float* ew     = (const float*)d_in[2];
    const float* Wrel1  = (const float*)d_in[3];
    const float* Wroot1 = (const float*)d_in[4];
    const float* b1     = (const float*)d_in[5];
    const float* Wrel2  = (const float*)d_in[6];
    const float* Wroot2 = (const float*)d_in[7];
    const float* b2     = (const float*)d_in[8];
    float* out = (float*)d_out;

    const int* src = ei;
    const int* dst = ei + E_EDGES;

    // Workspace (4B units). staged_p+staged_w (10.8MB) alias xrelh+xrooth
    // (12.8MB) — staged dead after k_binB2; k1_mfma writes xrelh after.
    char* ws = (char*)d_ws;
    int*   deg           = (int*)ws;                            // N
    int*   bucket_cursor = deg + N_NODES;                       // 256
    unsigned short* wt_g = (unsigned short*)(bucket_cursor + 256); // 8192 us
    int*   offsets       = (int*)(wt_g + 64 * 128);             // N
    int*   csr_src       = offsets + N_NODES;                   // E
    unsigned short* csr_w = (unsigned short*)(csr_src + E_EDGES); // E us
    unsigned short* xrelh = csr_w + E_EDGES;                    // 32N us
    unsigned short* xrooth = xrelh + (size_t)N_NODES * H_MID;   // 32N us
    float* h2rel         = (float*)(xrooth + (size_t)N_NODES * H_MID); // 5N
    float* h2root        = h2rel + (size_t)N_NODES * C_OUT;     // 5N
    int*   staged_p      = (int*)xrelh;                         // alias
    unsigned short* staged_w = (unsigned short*)(staged_p + (size_t)NBKT * BCAP);

    // --- prep: zero cursors + bf16 W panel ---
    k_prep<<<1, 256, 0, stream>>>(Wrel1, Wroot1, bucket_cursor, wt_g);

    // --- binned CSR build ---
    k_binA<<<(E_EDGES + 2047) / 2048, 1024, 0, stream>>>(src, dst, ew,
                                                         bucket_cursor,
                                                         staged_p, staged_w);
    k_binB2<<<NBKT, 1024, 0, stream>>>(bucket_cursor, staged_p, staged_w,
                                       deg, offsets, csr_src, csr_w);

    // --- dense projections via MFMA (after staging is dead) ---
    k1_mfma<<<(N_NODES + 63) / 64, 256, 0, stream>>>(x, wt_g, b1,
                                                     xrelh, xrooth);

    // --- layer 1 fused gather + node update + layer-2 projections ---
    k_layer1<<<N_NODES / 32, 512, 0, stream>>>(offsets, deg, csr_src, csr_w,
                                               xrelh, xrooth, Wrel2, Wroot2, b2,
                                               h2rel, h2root);

    // --- layer 2 gather + log_softmax (fused) ---
    k_layer2<<<N_NODES / 32, 256, 0, stream>>>(offsets, deg, csr_src,
                                               h2rel, h2root, out);
}